// Round 14
// baseline (238.815 us; speedup 1.0000x reference)
//
#include <hip/hip_runtime.h>

#define S_LEN 2048
#define D_MODEL 1024
#define NH 16
#define DH 64

typedef __bf16 bf16x8 __attribute__((ext_vector_type(8)));
typedef __bf16 bf16x4 __attribute__((ext_vector_type(4)));
typedef float f32x4 __attribute__((ext_vector_type(4)));

__device__ __forceinline__ unsigned short f2bf(float f) {
  unsigned int x = __float_as_uint(f);
  x += 0x7fffu + ((x >> 16) & 1u);  // RNE
  return (unsigned short)(x >> 16);
}

__device__ __forceinline__ bf16x4 cvt4(f32x4 v) {
  return __builtin_convertvector(v, bf16x4);
}

__device__ __forceinline__ float exp2raw(float x) {
#if __has_builtin(__builtin_amdgcn_exp2f)
  return __builtin_amdgcn_exp2f(x);
#else
  return exp2f(x);
#endif
}

__device__ __forceinline__ f32x4 mfma16(bf16x8 a, bf16x8 b, f32x4 c) {
  return __builtin_amdgcn_mfma_f32_16x16x32_bf16(a, b, c, 0, 0, 0);
}

__device__ __forceinline__ void gl2lds(const unsigned short* g, unsigned short* l) {
  __builtin_amdgcn_global_load_lds(
      (__attribute__((address_space(1))) void*)g,
      (__attribute__((address_space(3))) void*)l, 16, 0, 0);
}

// ---- fused prep: pack mask bits (blocks 0..32767) + fp32->bf16 convert ----
__global__ __launch_bounds__(256) void prep_kernel(
    const float* __restrict__ q, const float* __restrict__ wq,
    const float* __restrict__ wk, const float* __restrict__ wv,
    const float* __restrict__ wo, const int* __restrict__ mask,
    unsigned short* __restrict__ qbf, unsigned short* __restrict__ wbf,
    unsigned long long* __restrict__ bits) {
  const int bx = blockIdx.x;
  if (bx < 32768) {  // pack mask: 1 bit per (b,q,key), lane i <-> bit i
    int i = bx * 256 + threadIdx.x;
    unsigned long long bal = __ballot(mask[i] != 0);
    if ((threadIdx.x & 63) == 0) bits[i >> 6] = bal;
  } else {  // convert 8 floats per thread
    const long t = (long)(bx - 32768) * 256 + threadIdx.x;
    const float* src;
    unsigned short* dst;
    long e;
    if (t < 524288) { src = q; dst = qbf; e = t * 8; }
    else {
      long u = t - 524288;
      int wi = (int)(u >> 17);
      e = (u & 131071) * 8;
      src = wi == 0 ? wq : wi == 1 ? wk : wi == 2 ? wv : wo;
      dst = wbf + (long)wi * 1048576;
    }
    float4 a = *(const float4*)(src + e);
    float4 b = *(const float4*)(src + e + 4);
    ushort4 p0 = {f2bf(a.x), f2bf(a.y), f2bf(a.z), f2bf(a.w)};
    ushort4 p1 = {f2bf(b.x), f2bf(b.y), f2bf(b.z), f2bf(b.w)};
    *(ushort4*)(dst + e) = p0;
    *(ushort4*)(dst + e + 4) = p1;
  }
}

// ---- fused QKV: C = A(4096x1024) @ [Wq;Wk;Wv](3072x1024)^T; BK=64 ----
// (R4 structure, verified best: 128x128 tile, 4 waves 2x2, XOR-swizzled LDS,
// glds width 16, direct epilogue)
__global__ __launch_bounds__(256) void gemm_qkv(
    const unsigned short* __restrict__ A, const unsigned short* __restrict__ W3,
    unsigned short* __restrict__ qb, unsigned short* __restrict__ kb,
    unsigned short* __restrict__ vt, float qscale) {
  __shared__ unsigned short As[128 * 64];  // 16 KB
  __shared__ unsigned short Bs[128 * 64];
  const int tid = threadIdx.x, lane = tid & 63, wid = tid >> 6;
  const int wm = wid >> 1, wn = wid & 1;
  const int quad = lane >> 4, c = lane & 15, cx = c & 7;
  const int nG = blockIdx.x * 128;
  const int wi = nG >> 10, nn0 = nG & 1023;
  const int m0 = blockIdx.y * 128;
  const unsigned short* Bsrc = W3 + (size_t)wi * 1048576;
  const int srow = lane >> 3;
  const int schk = ((lane & 7) ^ srow) * 8;
  const unsigned short* ag = A + (size_t)(m0 + wid * 32 + srow) * 1024 + schk;
  const unsigned short* bg = Bsrc + (size_t)(nn0 + wid * 32 + srow) * 1024 + schk;
  f32x4 acc[4][4] = {};
  for (int kk = 0; kk < 1024; kk += 64) {
#pragma unroll
    for (int i = 0; i < 4; ++i) {
      gl2lds(ag + (size_t)(i * 8) * 1024 + kk, &As[(wid * 32 + i * 8) * 64]);
      gl2lds(bg + (size_t)(i * 8) * 1024 + kk, &Bs[(wid * 32 + i * 8) * 64]);
    }
    __syncthreads();
#pragma unroll
    for (int kc = 0; kc < 2; ++kc) {
      bf16x8 a[4], b[4];
#pragma unroll
      for (int mt = 0; mt < 4; ++mt)
        a[mt] = *(const bf16x8*)(
            &As[(wm * 64 + mt * 16 + c) * 64 + ((kc * 4 + quad) ^ cx) * 8]);
#pragma unroll
      for (int nt = 0; nt < 4; ++nt)
        b[nt] = *(const bf16x8*)(
            &Bs[(wn * 64 + nt * 16 + c) * 64 + ((kc * 4 + quad) ^ cx) * 8]);
#pragma unroll
      for (int mt = 0; mt < 4; ++mt)
#pragma unroll
        for (int nt = 0; nt < 4; ++nt)
          acc[mt][nt] = mfma16(a[mt], b[nt], acc[mt][nt]);
    }
    __syncthreads();
  }
#pragma unroll
  for (int mt = 0; mt < 4; ++mt) {
#pragma unroll
    for (int nt = 0; nt < 4; ++nt) {
      const int mb = m0 + wm * 64 + mt * 16 + quad * 4;
      const int n = nn0 + wn * 64 + nt * 16 + c;
      const int hh = n >> 6, d = n & 63;
      const int bb = mb >> 11, ss = mb & 2047;
      if (wi == 0) {
#pragma unroll
        for (int r = 0; r < 4; ++r)
          qb[(size_t)((bb * NH + hh) * S_LEN + ss + r) * DH + d] =
              f2bf(acc[mt][nt][r] * qscale);
      } else if (wi == 1) {
#pragma unroll
        for (int r = 0; r < 4; ++r)
          kb[(size_t)((bb * NH + hh) * S_LEN + ss + r) * DH + d] =
              f2bf(acc[mt][nt][r]);
      } else {  // V^T: 4 regs = 4 consecutive s
        *(bf16x4*)(vt + (size_t)((bb * NH + hh) * DH + d) * S_LEN + ss) =
            cvt4(acc[mt][nt]);
      }
    }
  }
}

// ---- O projection: out = ctx(4096x1024) @ Wo^T + bo ----
// R18: SPLIT-K=2 with 128x128 tile. The old 128x64 tile gave each wave only
// 8 MFMA per 6 ds_read_b128 (LDS-issue-bound, 1.33 ratio); 128x128/acc[4][4]
// restores the 2.0 ratio but alone would collapse the grid to 256 blocks
// (1 block/CU). Split-K=2 keeps 512 blocks = 2 blocks/CU: each block does
// K in [z*512, z*512+512) with the proven R4 BK=64 loop, epilogue is
// atomicAdd f32 (harness memsets out to 0 before the verify launch; 2-way
// f32 accumulation is order-robust vs the 6.25e-3 threshold). Split 0 adds
// the bias. 8 barriers/block, 32 MFMA/wave/period at 16 reads.
__global__ __launch_bounds__(256) void gemm_out(
    const unsigned short* __restrict__ A, const unsigned short* __restrict__ W,
    float* __restrict__ out, const float* __restrict__ bias) {
  __shared__ unsigned short As[128 * 64];  // 16 KB
  __shared__ unsigned short Bs[128 * 64];  // 16 KB
  const int tid = threadIdx.x, lane = tid & 63, wid = tid >> 6;
  const int wm = wid >> 1, wn = wid & 1;
  const int quad = lane >> 4, c = lane & 15, cx = c & 7;
  const int n0 = blockIdx.x * 128, m0 = blockIdx.y * 128;
  const int k0 = blockIdx.z * 512;
  const int srow = lane >> 3;
  const int schk = ((lane & 7) ^ srow) * 8;
  const unsigned short* ag =
      A + (size_t)(m0 + wid * 32 + srow) * 1024 + k0 + schk;
  const unsigned short* bg =
      W + (size_t)(n0 + wid * 32 + srow) * 1024 + k0 + schk;
  f32x4 acc[4][4] = {};
  for (int kk = 0; kk < 512; kk += 64) {
#pragma unroll
    for (int i = 0; i < 4; ++i) {
      gl2lds(ag + (size_t)(i * 8) * 1024 + kk, &As[(wid * 32 + i * 8) * 64]);
      gl2lds(bg + (size_t)(i * 8) * 1024 + kk, &Bs[(wid * 32 + i * 8) * 64]);
    }
    __syncthreads();
#pragma unroll
    for (int kc = 0; kc < 2; ++kc) {
      bf16x8 a[4], b[4];
#pragma unroll
      for (int mt = 0; mt < 4; ++mt)
        a[mt] = *(const bf16x8*)(
            &As[(wm * 64 + mt * 16 + c) * 64 + ((kc * 4 + quad) ^ cx) * 8]);
#pragma unroll
      for (int nt = 0; nt < 4; ++nt)
        b[nt] = *(const bf16x8*)(
            &Bs[(wn * 64 + nt * 16 + c) * 64 + ((kc * 4 + quad) ^ cx) * 8]);
#pragma unroll
      for (int mt = 0; mt < 4; ++mt)
#pragma unroll
        for (int nt = 0; nt < 4; ++nt)
          acc[mt][nt] = mfma16(a[mt], b[nt], acc[mt][nt]);
    }
    __syncthreads();
  }
  const bool addb = (blockIdx.z == 0);
#pragma unroll
  for (int mt = 0; mt < 4; ++mt) {
#pragma unroll
    for (int nt = 0; nt < 4; ++nt) {
      const int mb = m0 + wm * 64 + mt * 16 + quad * 4;
      const int n = n0 + wn * 64 + nt * 16 + c;
      const float bv = addb ? bias[n] : 0.f;
#pragma unroll
      for (int r = 0; r < 4; ++r)
        atomicAdd(&out[(size_t)(mb + r) * D_MODEL + n], acc[mt][nt][r] + bv);
    }
  }
}

// ---- flash attention, static-max softmax, 64 q per wave ----
// R11 attn (verified best): KVBLK=128 single-buffer, sigma-permuted K
// staging, in-register P, MFMA-pipe denominator, setprio around MFMA
// clusters.
__global__ __launch_bounds__(256, 2) void attn_kernel(
    const unsigned short* __restrict__ qb, const unsigned short* __restrict__ kb,
    const unsigned short* __restrict__ vt,
    const unsigned long long* __restrict__ mbits,
    unsigned short* __restrict__ ctx) {
  const int h = blockIdx.x, qt = blockIdx.y, b = blockIdx.z;
  const int bh = b * NH + h;
  const int tid = threadIdx.x, lane = tid & 63, wid = tid >> 6;
  const int quad = lane >> 4, c = lane & 15, cx = c & 7;
  const int qw = wid & 1, kh = wid >> 1;
  const int q0 = qt * 128;
  // KV staging: 2 sub-tiles x 32 KB = 64 KB; merge scratch overlays it.
  __shared__ __align__(16) char smem[65536];
  unsigned short* KVb = (unsigned short*)smem;

  const int qbase = q0 + qw * 64;
  const unsigned short* qp = qb + (size_t)(bh * S_LEN + qbase + c) * DH;
  bf16x8 bq[4][2];
#pragma unroll
  for (int sub = 0; sub < 4; ++sub) {
    bq[sub][0] = *(const bf16x8*)(qp + sub * 16 * DH + quad * 8);
    bq[sub][1] = *(const bf16x8*)(qp + sub * 16 * DH + 32 + quad * 8);
  }

  const bf16x8 onesv = {(__bf16)1.f, (__bf16)1.f, (__bf16)1.f, (__bf16)1.f,
                        (__bf16)1.f, (__bf16)1.f, (__bf16)1.f, (__bf16)1.f};

  f32x4 o[4][4] = {};
  float lacc[4] = {0.f, 0.f, 0.f, 0.f};
  const unsigned long long* mq0 =
      mbits + (size_t)(b * S_LEN + qbase + c) * 32 + kh * 16;

  const int srow = lane >> 3, schk = ((lane & 7) ^ srow) * 8;

  const unsigned short* gKb =
      kb + (size_t)(bh * S_LEN + (wid & 1) * 1024) * DH + schk;
  const unsigned short* gV =
      vt + (size_t)(bh * DH + srow) * S_LEN + (wid - 2) * 1024 + schk;

  for (int kt = 0; kt < 1024; kt += 128) {
    // stage both 64-key sub-tiles of this 128-key period
    if (wid < 2) {
#pragma unroll
      for (int hf = 0; hf < 2; ++hf)
#pragma unroll
        for (int i = 0; i < 8; ++i) {
          const int t = i * 8 + srow;
          const int st = (t & 0x23) | ((t >> 2) & 0x04) | ((t << 1) & 0x18);
          gl2lds(gKb + (size_t)(kt + hf * 64 + st) * DH,
                 &KVb[hf * 16384 + wid * 4096 + i * 512]);
        }
    } else {
#pragma unroll
      for (int hf = 0; hf < 2; ++hf)
#pragma unroll
        for (int i = 0; i < 8; ++i)
          gl2lds(gV + (size_t)(i * 8) * S_LEN + kt + hf * 64,
                 &KVb[hf * 16384 + wid * 4096 + i * 512]);
    }
    __syncthreads();  // (1) staging complete

#pragma unroll
    for (int hf = 0; hf < 2; ++hf) {
      const unsigned short* Ksh = KVb + hf * 16384 + kh * 4096;
      const unsigned short* Vsh = KVb + hf * 16384 + (2 + kh) * 4096;
      const int mi = (kt >> 6) + hf;

      // K-tile fragments, kept in regs across all 4 q-subgroups
      bf16x8 kf[8];
#pragma unroll
      for (int g = 0; g < 4; ++g) {
        const int rho = g * 16 + c;
        kf[2 * g] = *(const bf16x8*)(&Ksh[rho * 64 + (quad ^ cx) * 8]);
        kf[2 * g + 1] =
            *(const bf16x8*)(&Ksh[rho * 64 + ((4 + quad) ^ cx) * 8]);
      }

      bf16x8 bps[4][2];  // PV B-fragments, built in registers
#pragma unroll
      for (int sub = 0; sub < 4; ++sub) {
        f32x4 s[4];
        __builtin_amdgcn_s_setprio(1);
#pragma unroll
        for (int g = 0; g < 4; ++g) {
          f32x4 z = {};
          z = mfma16(kf[2 * g], bq[sub][0], z);
          z = mfma16(kf[2 * g + 1], bq[sub][1], z);
          s[g] = z;
        }
        __builtin_amdgcn_s_setprio(0);
        const unsigned long long w64 = mq0[sub * 512 + mi];
        const unsigned int wlo = (unsigned int)w64;
        const unsigned int whi = (unsigned int)(w64 >> 32);
        f32x4 p[4];
#pragma unroll
        for (int g = 0; g < 4; ++g) {
          // permuted key for (g,quad,r): (g>>1)*32 + quad*8 + (g&1)*4 + r
          const unsigned int bits =
              ((g & 2) ? whi : wlo) >> (quad * 8 + (g & 1) * 4);
#pragma unroll
          for (int r = 0; r < 4; ++r) {
            const float e = exp2raw(s[g][r]);
            p[g][r] = ((bits >> r) & 1u) ? 0.f : e;
          }
        }
        union { bf16x8 v; bf16x4 h[2]; } u0, u1;
        u0.h[0] = cvt4(p[0]); u0.h[1] = cvt4(p[1]);
        u1.h[0] = cvt4(p[2]); u1.h[1] = cvt4(p[3]);
        bps[sub][0] = u0.v;
        bps[sub][1] = u1.v;
        // denominator on the MFMA pipe: rows of ones x P^T = column sums;
        // every lane's z[0] = sum over this sub-tile's 64 keys for its q.
        f32x4 zs = {};
        zs = mfma16(onesv, bps[sub][0], zs);
        zs = mfma16(onesv, bps[sub][1], zs);
        lacc[sub] += zs[0];
      }

      // ctx^T += V^T . P^T  (V-frag read once, P straight from registers)
      __builtin_amdgcn_s_setprio(1);
#pragma unroll
      for (int ks = 0; ks < 2; ++ks) {
#pragma unroll
        for (int nt = 0; nt < 4; ++nt) {
          bf16x8 av = *(const bf16x8*)(
              &Vsh[(nt * 16 + c) * 64 + ((ks * 4 + quad) ^ cx) * 8]);
#pragma unroll
          for (int sub = 0; sub < 4; ++sub)
            o[sub][nt] = mfma16(av, bps[sub][ks], o[sub][nt]);
        }
      }
      __builtin_amdgcn_s_setprio(0);
    }
    __syncthreads();  // (2) both sub-tiles consumed; safe to restage
  }

  // merge key-halves via smem (KV dead after final barrier):
  // 8 panels of 16q x 68 floats + l array
  float* mrg = (float*)smem;
  float* ml = mrg + 8 * 1088;
  if (kh == 1) {
#pragma unroll
    for (int sub = 0; sub < 4; ++sub) {
      float* mo = mrg + (qw * 4 + sub) * 1088;
#pragma unroll
      for (int nt = 0; nt < 4; ++nt)
        *(f32x4*)(mo + c * 68 + nt * 16 + quad * 4) = o[sub][nt];
      if (quad == 0) ml[(qw * 4 + sub) * 16 + c] = lacc[sub];
    }
  }
  __syncthreads();
  if (kh == 0) {
#pragma unroll
    for (int sub = 0; sub < 4; ++sub) {
      const int pp = qw * 4 + sub;
      const float inv = 1.0f / (lacc[sub] + ml[pp * 16 + c]);
      const int q = qbase + sub * 16 + c;
      const float* mo = mrg + pp * 1088;
#pragma unroll
      for (int nt = 0; nt < 4; ++nt) {
        f32x4 ob = *(const f32x4*)(mo + c * 68 + nt * 16 + quad * 4);
        f32x4 rr = (o[sub][nt] + ob) * inv;
        *(bf16x4*)(ctx + (size_t)(b * S_LEN + q) * D_MODEL + h * DH + nt * 16 +
                   quad * 4) = cvt4(rr);
      }
    }
  }
}

extern "C" void kernel_launch(void* const* d_in, const int* in_sizes, int n_in,
                              void* d_out, int out_size, void* d_ws, size_t ws_size,
                              hipStream_t stream) {
  const float* query = (const float*)d_in[0];
  const int* mask = (const int*)d_in[1];
  const float* Wq = (const float*)d_in[2];
  const float* Wk = (const float*)d_in[3];
  const float* Wv = (const float*)d_in[4];
  const float* Wo = (const float*)d_in[5];
  const float* bo = (const float*)d_in[6];
  float* out = (float*)d_out;

  char* ws = (char*)d_ws;
  const size_t MB = 1024 * 1024;
  unsigned short* qbf = (unsigned short*)(ws);           // 8 MB; reused as ctx
  unsigned short* wbf = (unsigned short*)(ws + 8 * MB);  // 8 MB (Wq,Wk,Wv,Wo bf16)
  unsigned short* qb = (unsigned short*)(ws + 16 * MB);  // 8 MB
  unsigned short* kb = (unsigned short*)(ws + 24 * MB);  // 8 MB
  unsigned short* vt = (unsigned short*)(ws + 32 * MB);  // 8 MB
  unsigned long long* mb = (unsigned long long*)(ws + 40 * MB);  // 1 MB
  unsigned short* ctx = qbf;

  prep_kernel<<<32768 + 4096, 256, 0, stream>>>(query, Wq, Wk, Wv, Wo, mask,
                                                qbf, wbf, mb);

  // Q scaled by 1/sqrt(dh) * log2(e): softmax in exp2 domain
  gemm_qkv<<<dim3(3072 / 128, 4096 / 128), 256, 0, stream>>>(
      qbf, wbf, qb, kb, vt, 0.18033688f);

  attn_kernel<<<dim3(NH, S_LEN / 128, 2), 256, 0, stream>>>(qb, kb, vt, mb,
                                                            ctx);

  // split-K=2: 128x128 tiles, atomicAdd epilogue (out is zeroed by harness)
  gemm_out<<<dim3(1024 / 128, 4096 / 128, 2), 256, 0, stream>>>(
      ctx, wbf + 3 * 1048576, out, bo);
}

// Round 15
// 212.342 us; speedup vs baseline: 1.1247x; 1.1247x over previous
//
#include <hip/hip_runtime.h>

#define S_LEN 2048
#define D_MODEL 1024
#define NH 16
#define DH 64

typedef __bf16 bf16x8 __attribute__((ext_vector_type(8)));
typedef __bf16 bf16x4 __attribute__((ext_vector_type(4)));
typedef float f32x4 __attribute__((ext_vector_type(4)));
typedef unsigned long long ull2 __attribute__((ext_vector_type(2)));

__device__ __forceinline__ unsigned short f2bf(float f) {
  unsigned int x = __float_as_uint(f);
  x += 0x7fffu + ((x >> 16) & 1u);  // RNE
  return (unsigned short)(x >> 16);
}

__device__ __forceinline__ bf16x4 cvt4(f32x4 v) {
  return __builtin_convertvector(v, bf16x4);
}

__device__ __forceinline__ float exp2raw(float x) {
#if __has_builtin(__builtin_amdgcn_exp2f)
  return __builtin_amdgcn_exp2f(x);
#else
  return exp2f(x);
#endif
}

__device__ __forceinline__ f32x4 mfma16(bf16x8 a, bf16x8 b, f32x4 c) {
  return __builtin_amdgcn_mfma_f32_16x16x32_bf16(a, b, c, 0, 0, 0);
}

__device__ __forceinline__ void gl2lds(const unsigned short* g, unsigned short* l) {
  __builtin_amdgcn_global_load_lds(
      (__attribute__((address_space(1))) void*)g,
      (__attribute__((address_space(3))) void*)l, 16, 0, 0);
}

// ---- fused prep: pack mask bits (dense blocks 0..8191) + fp32->bf16 ----
// R19: mask path densified (verified bit-identical form from R14/R17):
// 8192 blocks, each wave packs 4 u64-words via 4 coalesced dword loads +
// 4 ballots + two 16-B ull2 stores. 4x fewer blocks, 2x wider stores.
__global__ __launch_bounds__(256) void prep_kernel(
    const float* __restrict__ q, const float* __restrict__ wq,
    const float* __restrict__ wk, const float* __restrict__ wv,
    const float* __restrict__ wo, const int* __restrict__ mask,
    unsigned short* __restrict__ qbf, unsigned short* __restrict__ wbf,
    unsigned long long* __restrict__ bits) {
  const int bx = blockIdx.x;
  if (bx < 8192) {  // pack mask: 16 u64-words per block, 4 per wave
    const int wv = threadIdx.x >> 6, ln = threadIdx.x & 63;
    const long wbase = (long)bx * 16 + wv * 4;  // u64-word index
    unsigned long long w[4];
#pragma unroll
    for (int j = 0; j < 4; ++j)
      w[j] = __ballot(mask[(wbase + j) * 64 + ln] != 0);
    if (ln == 0) {
      ull2 lo = {w[0], w[1]}, hi = {w[2], w[3]};
      *(ull2*)(bits + wbase) = lo;
      *(ull2*)(bits + wbase + 2) = hi;
    }
  } else {  // convert 8 floats per thread
    const long t = (long)(bx - 8192) * 256 + threadIdx.x;
    const float* src;
    unsigned short* dst;
    long e;
    if (t < 524288) { src = q; dst = qbf; e = t * 8; }
    else {
      long u = t - 524288;
      int wi = (int)(u >> 17);
      e = (u & 131071) * 8;
      src = wi == 0 ? wq : wi == 1 ? wk : wi == 2 ? wv : wo;
      dst = wbf + (long)wi * 1048576;
    }
    float4 a = *(const float4*)(src + e);
    float4 b = *(const float4*)(src + e + 4);
    ushort4 p0 = {f2bf(a.x), f2bf(a.y), f2bf(a.z), f2bf(a.w)};
    ushort4 p1 = {f2bf(b.x), f2bf(b.y), f2bf(b.z), f2bf(b.w)};
    *(ushort4*)(dst + e) = p0;
    *(ushort4*)(dst + e + 4) = p1;
  }
}

// ---- fused QKV: C = A(4096x1024) @ [Wq;Wk;Wv](3072x1024)^T; BK=64 ----
// (R4 structure, verified best: 128x128 tile, 4 waves 2x2, XOR-swizzled LDS,
// glds width 16, direct epilogue)
__global__ __launch_bounds__(256) void gemm_qkv(
    const unsigned short* __restrict__ A, const unsigned short* __restrict__ W3,
    unsigned short* __restrict__ qb, unsigned short* __restrict__ kb,
    unsigned short* __restrict__ vt, float qscale) {
  __shared__ unsigned short As[128 * 64];  // 16 KB
  __shared__ unsigned short Bs[128 * 64];
  const int tid = threadIdx.x, lane = tid & 63, wid = tid >> 6;
  const int wm = wid >> 1, wn = wid & 1;
  const int quad = lane >> 4, c = lane & 15, cx = c & 7;
  const int nG = blockIdx.x * 128;
  const int wi = nG >> 10, nn0 = nG & 1023;
  const int m0 = blockIdx.y * 128;
  const unsigned short* Bsrc = W3 + (size_t)wi * 1048576;
  const int srow = lane >> 3;
  const int schk = ((lane & 7) ^ srow) * 8;
  const unsigned short* ag = A + (size_t)(m0 + wid * 32 + srow) * 1024 + schk;
  const unsigned short* bg = Bsrc + (size_t)(nn0 + wid * 32 + srow) * 1024 + schk;
  f32x4 acc[4][4] = {};
  for (int kk = 0; kk < 1024; kk += 64) {
#pragma unroll
    for (int i = 0; i < 4; ++i) {
      gl2lds(ag + (size_t)(i * 8) * 1024 + kk, &As[(wid * 32 + i * 8) * 64]);
      gl2lds(bg + (size_t)(i * 8) * 1024 + kk, &Bs[(wid * 32 + i * 8) * 64]);
    }
    __syncthreads();
#pragma unroll
    for (int kc = 0; kc < 2; ++kc) {
      bf16x8 a[4], b[4];
#pragma unroll
      for (int mt = 0; mt < 4; ++mt)
        a[mt] = *(const bf16x8*)(
            &As[(wm * 64 + mt * 16 + c) * 64 + ((kc * 4 + quad) ^ cx) * 8]);
#pragma unroll
      for (int nt = 0; nt < 4; ++nt)
        b[nt] = *(const bf16x8*)(
            &Bs[(wn * 64 + nt * 16 + c) * 64 + ((kc * 4 + quad) ^ cx) * 8]);
#pragma unroll
      for (int mt = 0; mt < 4; ++mt)
#pragma unroll
        for (int nt = 0; nt < 4; ++nt)
          acc[mt][nt] = mfma16(a[mt], b[nt], acc[mt][nt]);
    }
    __syncthreads();
  }
#pragma unroll
  for (int mt = 0; mt < 4; ++mt) {
#pragma unroll
    for (int nt = 0; nt < 4; ++nt) {
      const int mb = m0 + wm * 64 + mt * 16 + quad * 4;
      const int n = nn0 + wn * 64 + nt * 16 + c;
      const int hh = n >> 6, d = n & 63;
      const int bb = mb >> 11, ss = mb & 2047;
      if (wi == 0) {
#pragma unroll
        for (int r = 0; r < 4; ++r)
          qb[(size_t)((bb * NH + hh) * S_LEN + ss + r) * DH + d] =
              f2bf(acc[mt][nt][r] * qscale);
      } else if (wi == 1) {
#pragma unroll
        for (int r = 0; r < 4; ++r)
          kb[(size_t)((bb * NH + hh) * S_LEN + ss + r) * DH + d] =
              f2bf(acc[mt][nt][r]);
      } else {  // V^T: 4 regs = 4 consecutive s
        *(bf16x4*)(vt + (size_t)((bb * NH + hh) * DH + d) * S_LEN + ss) =
            cvt4(acc[mt][nt]);
      }
    }
  }
}

// ---- O projection: out = ctx(4096x1024) @ Wo^T + bo; BK=128 (R11) ----
__global__ __launch_bounds__(256) void gemm_out(
    const unsigned short* __restrict__ A, const unsigned short* __restrict__ W,
    float* __restrict__ out, const float* __restrict__ bias) {
  __shared__ unsigned short As[128 * 128];  // 32 KB
  __shared__ unsigned short Bs[64 * 128];   // 16 KB
  const int tid = threadIdx.x, lane = tid & 63, wid = tid >> 6;
  const int wm = wid >> 1, wn = wid & 1;
  const int quad = lane >> 4, c = lane & 15, cx = c & 7;
  const int n0 = blockIdx.x * 64, m0 = blockIdx.y * 128;
  const int srow4 = lane >> 4, sch = lane & 15;
  const int co0 = (sch ^ srow4) * 8;
  const int co1 = (sch ^ (4 + srow4)) * 8;
  const unsigned short* agr = A + (size_t)(m0 + wid * 32 + srow4) * 1024;
  const unsigned short* bgr = W + (size_t)(n0 + wid * 16 + srow4) * 1024;
  f32x4 acc[4][2] = {};
  for (int kk = 0; kk < 1024; kk += 128) {
#pragma unroll
    for (int i = 0; i < 8; ++i)
      gl2lds(agr + (size_t)(i * 4) * 1024 + kk + ((i & 1) ? co1 : co0),
             &As[(wid * 32 + i * 4) * 128]);
#pragma unroll
    for (int i = 0; i < 4; ++i)
      gl2lds(bgr + (size_t)(i * 4) * 1024 + kk + ((i & 1) ? co1 : co0),
             &Bs[(wid * 16 + i * 4) * 128]);
    __syncthreads();
#pragma unroll
    for (int kc = 0; kc < 4; ++kc) {
      bf16x8 a[4], b[2];
#pragma unroll
      for (int mt = 0; mt < 4; ++mt)
        a[mt] = *(const bf16x8*)(
            &As[(wm * 64 + mt * 16 + c) * 128 + ((kc * 4 + quad) ^ cx) * 8]);
#pragma unroll
      for (int nt = 0; nt < 2; ++nt)
        b[nt] = *(const bf16x8*)(
            &Bs[(wn * 32 + nt * 16 + c) * 128 + ((kc * 4 + quad) ^ cx) * 8]);
#pragma unroll
      for (int mt = 0; mt < 4; ++mt)
#pragma unroll
        for (int nt = 0; nt < 2; ++nt)
          acc[mt][nt] = mfma16(a[mt], b[nt], acc[mt][nt]);
    }
    __syncthreads();
  }
#pragma unroll
  for (int mt = 0; mt < 4; ++mt) {
#pragma unroll
    for (int nt = 0; nt < 2; ++nt) {
      const int mb = m0 + wm * 64 + mt * 16 + quad * 4;
      const int n = n0 + wn * 32 + nt * 16 + c;
      const float bv = bias[n];
#pragma unroll
      for (int r = 0; r < 4; ++r)
        out[(size_t)(mb + r) * D_MODEL + n] = acc[mt][nt][r] + bv;
    }
  }
}

// ---- flash attention, static-max softmax, 64 q per wave ----
// R11 attn (verified best): KVBLK=128 single-buffer, sigma-permuted K
// staging, in-register P, MFMA-pipe denominator, setprio around MFMA
// clusters.
__global__ __launch_bounds__(256, 2) void attn_kernel(
    const unsigned short* __restrict__ qb, const unsigned short* __restrict__ kb,
    const unsigned short* __restrict__ vt,
    const unsigned long long* __restrict__ mbits,
    unsigned short* __restrict__ ctx) {
  const int h = blockIdx.x, qt = blockIdx.y, b = blockIdx.z;
  const int bh = b * NH + h;
  const int tid = threadIdx.x, lane = tid & 63, wid = tid >> 6;
  const int quad = lane >> 4, c = lane & 15, cx = c & 7;
  const int qw = wid & 1, kh = wid >> 1;
  const int q0 = qt * 128;
  // KV staging: 2 sub-tiles x 32 KB = 64 KB; merge scratch overlays it.
  __shared__ __align__(16) char smem[65536];
  unsigned short* KVb = (unsigned short*)smem;

  const int qbase = q0 + qw * 64;
  const unsigned short* qp = qb + (size_t)(bh * S_LEN + qbase + c) * DH;
  bf16x8 bq[4][2];
#pragma unroll
  for (int sub = 0; sub < 4; ++sub) {
    bq[sub][0] = *(const bf16x8*)(qp + sub * 16 * DH + quad * 8);
    bq[sub][1] = *(const bf16x8*)(qp + sub * 16 * DH + 32 + quad * 8);
  }

  const bf16x8 onesv = {(__bf16)1.f, (__bf16)1.f, (__bf16)1.f, (__bf16)1.f,
                        (__bf16)1.f, (__bf16)1.f, (__bf16)1.f, (__bf16)1.f};

  f32x4 o[4][4] = {};
  float lacc[4] = {0.f, 0.f, 0.f, 0.f};
  const unsigned long long* mq0 =
      mbits + (size_t)(b * S_LEN + qbase + c) * 32 + kh * 16;

  const int srow = lane >> 3, schk = ((lane & 7) ^ srow) * 8;

  const unsigned short* gKb =
      kb + (size_t)(bh * S_LEN + (wid & 1) * 1024) * DH + schk;
  const unsigned short* gV =
      vt + (size_t)(bh * DH + srow) * S_LEN + (wid - 2) * 1024 + schk;

  for (int kt = 0; kt < 1024; kt += 128) {
    // stage both 64-key sub-tiles of this 128-key period
    if (wid < 2) {
#pragma unroll
      for (int hf = 0; hf < 2; ++hf)
#pragma unroll
        for (int i = 0; i < 8; ++i) {
          const int t = i * 8 + srow;
          const int st = (t & 0x23) | ((t >> 2) & 0x04) | ((t << 1) & 0x18);
          gl2lds(gKb + (size_t)(kt + hf * 64 + st) * DH,
                 &KVb[hf * 16384 + wid * 4096 + i * 512]);
        }
    } else {
#pragma unroll
      for (int hf = 0; hf < 2; ++hf)
#pragma unroll
        for (int i = 0; i < 8; ++i)
          gl2lds(gV + (size_t)(i * 8) * S_LEN + kt + hf * 64,
                 &KVb[hf * 16384 + wid * 4096 + i * 512]);
    }
    __syncthreads();  // (1) staging complete

#pragma unroll
    for (int hf = 0; hf < 2; ++hf) {
      const unsigned short* Ksh = KVb + hf * 16384 + kh * 4096;
      const unsigned short* Vsh = KVb + hf * 16384 + (2 + kh) * 4096;
      const int mi = (kt >> 6) + hf;

      // K-tile fragments, kept in regs across all 4 q-subgroups
      bf16x8 kf[8];
#pragma unroll
      for (int g = 0; g < 4; ++g) {
        const int rho = g * 16 + c;
        kf[2 * g] = *(const bf16x8*)(&Ksh[rho * 64 + (quad ^ cx) * 8]);
        kf[2 * g + 1] =
            *(const bf16x8*)(&Ksh[rho * 64 + ((4 + quad) ^ cx) * 8]);
      }

      bf16x8 bps[4][2];  // PV B-fragments, built in registers
#pragma unroll
      for (int sub = 0; sub < 4; ++sub) {
        f32x4 s[4];
        __builtin_amdgcn_s_setprio(1);
#pragma unroll
        for (int g = 0; g < 4; ++g) {
          f32x4 z = {};
          z = mfma16(kf[2 * g], bq[sub][0], z);
          z = mfma16(kf[2 * g + 1], bq[sub][1], z);
          s[g] = z;
        }
        __builtin_amdgcn_s_setprio(0);
        const unsigned long long w64 = mq0[sub * 512 + mi];
        const unsigned int wlo = (unsigned int)w64;
        const unsigned int whi = (unsigned int)(w64 >> 32);
        f32x4 p[4];
#pragma unroll
        for (int g = 0; g < 4; ++g) {
          // permuted key for (g,quad,r): (g>>1)*32 + quad*8 + (g&1)*4 + r
          const unsigned int bits =
              ((g & 2) ? whi : wlo) >> (quad * 8 + (g & 1) * 4);
#pragma unroll
          for (int r = 0; r < 4; ++r) {
            const float e = exp2raw(s[g][r]);
            p[g][r] = ((bits >> r) & 1u) ? 0.f : e;
          }
        }
        union { bf16x8 v; bf16x4 h[2]; } u0, u1;
        u0.h[0] = cvt4(p[0]); u0.h[1] = cvt4(p[1]);
        u1.h[0] = cvt4(p[2]); u1.h[1] = cvt4(p[3]);
        bps[sub][0] = u0.v;
        bps[sub][1] = u1.v;
        // denominator on the MFMA pipe: rows of ones x P^T = column sums;
        // every lane's z[0] = sum over this sub-tile's 64 keys for its q.
        f32x4 zs = {};
        zs = mfma16(onesv, bps[sub][0], zs);
        zs = mfma16(onesv, bps[sub][1], zs);
        lacc[sub] += zs[0];
      }

      // ctx^T += V^T . P^T  (V-frag read once, P straight from registers)
      __builtin_amdgcn_s_setprio(1);
#pragma unroll
      for (int ks = 0; ks < 2; ++ks) {
#pragma unroll
        for (int nt = 0; nt < 4; ++nt) {
          bf16x8 av = *(const bf16x8*)(
              &Vsh[(nt * 16 + c) * 64 + ((ks * 4 + quad) ^ cx) * 8]);
#pragma unroll
          for (int sub = 0; sub < 4; ++sub)
            o[sub][nt] = mfma16(av, bps[sub][ks], o[sub][nt]);
        }
      }
      __builtin_amdgcn_s_setprio(0);
    }
    __syncthreads();  // (2) both sub-tiles consumed; safe to restage
  }

  // merge key-halves via smem (KV dead after final barrier):
  // 8 panels of 16q x 68 floats + l array
  float* mrg = (float*)smem;
  float* ml = mrg + 8 * 1088;
  if (kh == 1) {
#pragma unroll
    for (int sub = 0; sub < 4; ++sub) {
      float* mo = mrg + (qw * 4 + sub) * 1088;
#pragma unroll
      for (int nt = 0; nt < 4; ++nt)
        *(f32x4*)(mo + c * 68 + nt * 16 + quad * 4) = o[sub][nt];
      if (quad == 0) ml[(qw * 4 + sub) * 16 + c] = lacc[sub];
    }
  }
  __syncthreads();
  if (kh == 0) {
#pragma unroll
    for (int sub = 0; sub < 4; ++sub) {
      const int pp = qw * 4 + sub;
      const float inv = 1.0f / (lacc[sub] + ml[pp * 16 + c]);
      const int q = qbase + sub * 16 + c;
      const float* mo = mrg + pp * 1088;
#pragma unroll
      for (int nt = 0; nt < 4; ++nt) {
        f32x4 ob = *(const f32x4*)(mo + c * 68 + nt * 16 + quad * 4);
        f32x4 rr = (o[sub][nt] + ob) * inv;
        *(bf16x4*)(ctx + (size_t)(b * S_LEN + q) * D_MODEL + h * DH + nt * 16 +
                   quad * 4) = cvt4(rr);
      }
    }
  }
}

extern "C" void kernel_launch(void* const* d_in, const int* in_sizes, int n_in,
                              void* d_out, int out_size, void* d_ws, size_t ws_size,
                              hipStream_t stream) {
  const float* query = (const float*)d_in[0];
  const int* mask = (const int*)d_in[1];
  const float* Wq = (const float*)d_in[2];
  const float* Wk = (const float*)d_in[3];
  const float* Wv = (const float*)d_in[4];
  const float* Wo = (const float*)d_in[5];
  const float* bo = (const float*)d_in[6];
  float* out = (float*)d_out;

  char* ws = (char*)d_ws;
  const size_t MB = 1024 * 1024;
  unsigned short* qbf = (unsigned short*)(ws);           // 8 MB; reused as ctx
  unsigned short* wbf = (unsigned short*)(ws + 8 * MB);  // 8 MB (Wq,Wk,Wv,Wo bf16)
  unsigned short* qb = (unsigned short*)(ws + 16 * MB);  // 8 MB
  unsigned short* kb = (unsigned short*)(ws + 24 * MB);  // 8 MB
  unsigned short* vt = (unsigned short*)(ws + 32 * MB);  // 8 MB
  unsigned long long* mb = (unsigned long long*)(ws + 40 * MB);  // 1 MB
  unsigned short* ctx = qbf;

  prep_kernel<<<8192 + 4096, 256, 0, stream>>>(query, Wq, Wk, Wv, Wo, mask,
                                               qbf, wbf, mb);

  // Q scaled by 1/sqrt(dh) * log2(e): softmax in exp2 domain
  gemm_qkv<<<dim3(3072 / 128, 4096 / 128), 256, 0, stream>>>(
      qbf, wbf, qb, kb, vt, 0.18033688f);

  attn_kernel<<<dim3(NH, S_LEN / 128, 2), 256, 0, stream>>>(qb, kb, vt, mb,
                                                            ctx);

  gemm_out<<<dim3(1024 / 64, 4096 / 128), 256, 0, stream>>>(
      ctx, wbf + 3 * 1048576, out, bo);
}

// Round 16
// 211.890 us; speedup vs baseline: 1.1271x; 1.0021x over previous
//
#include <hip/hip_runtime.h>

#define S_LEN 2048
#define D_MODEL 1024
#define NH 16
#define DH 64

typedef __bf16 bf16x8 __attribute__((ext_vector_type(8)));
typedef __bf16 bf16x4 __attribute__((ext_vector_type(4)));
typedef float f32x4 __attribute__((ext_vector_type(4)));
typedef unsigned long long ull2 __attribute__((ext_vector_type(2)));

__device__ __forceinline__ unsigned short f2bf(float f) {
  unsigned int x = __float_as_uint(f);
  x += 0x7fffu + ((x >> 16) & 1u);  // RNE
  return (unsigned short)(x >> 16);
}

__device__ __forceinline__ bf16x4 cvt4(f32x4 v) {
  return __builtin_convertvector(v, bf16x4);
}

__device__ __forceinline__ float exp2raw(float x) {
#if __has_builtin(__builtin_amdgcn_exp2f)
  return __builtin_amdgcn_exp2f(x);
#else
  return exp2f(x);
#endif
}

__device__ __forceinline__ f32x4 mfma16(bf16x8 a, bf16x8 b, f32x4 c) {
  return __builtin_amdgcn_mfma_f32_16x16x32_bf16(a, b, c, 0, 0, 0);
}

__device__ __forceinline__ void gl2lds(const unsigned short* g, unsigned short* l) {
  __builtin_amdgcn_global_load_lds(
      (__attribute__((address_space(1))) void*)g,
      (__attribute__((address_space(3))) void*)l, 16, 0, 0);
}

// ---- fused prep: pack mask bits (dense blocks 0..8191) + fp32->bf16 ----
// R19: 8192 blocks, each wave packs 4 u64-words via 4 coalesced dword loads
// + 4 ballots + two 16-B ull2 stores.
__global__ __launch_bounds__(256) void prep_kernel(
    const float* __restrict__ q, const float* __restrict__ wq,
    const float* __restrict__ wk, const float* __restrict__ wv,
    const float* __restrict__ wo, const int* __restrict__ mask,
    unsigned short* __restrict__ qbf, unsigned short* __restrict__ wbf,
    unsigned long long* __restrict__ bits) {
  const int bx = blockIdx.x;
  if (bx < 8192) {  // pack mask: 16 u64-words per block, 4 per wave
    const int wv = threadIdx.x >> 6, ln = threadIdx.x & 63;
    const long wbase = (long)bx * 16 + wv * 4;  // u64-word index
    unsigned long long w[4];
#pragma unroll
    for (int j = 0; j < 4; ++j)
      w[j] = __ballot(mask[(wbase + j) * 64 + ln] != 0);
    if (ln == 0) {
      ull2 lo = {w[0], w[1]}, hi = {w[2], w[3]};
      *(ull2*)(bits + wbase) = lo;
      *(ull2*)(bits + wbase + 2) = hi;
    }
  } else {  // convert 8 floats per thread
    const long t = (long)(bx - 8192) * 256 + threadIdx.x;
    const float* src;
    unsigned short* dst;
    long e;
    if (t < 524288) { src = q; dst = qbf; e = t * 8; }
    else {
      long u = t - 524288;
      int wi = (int)(u >> 17);
      e = (u & 131071) * 8;
      src = wi == 0 ? wq : wi == 1 ? wk : wi == 2 ? wv : wo;
      dst = wbf + (long)wi * 1048576;
    }
    float4 a = *(const float4*)(src + e);
    float4 b = *(const float4*)(src + e + 4);
    ushort4 p0 = {f2bf(a.x), f2bf(a.y), f2bf(a.z), f2bf(a.w)};
    ushort4 p1 = {f2bf(b.x), f2bf(b.y), f2bf(b.z), f2bf(b.w)};
    *(ushort4*)(dst + e) = p0;
    *(ushort4*)(dst + e + 4) = p1;
  }
}

// ---- fused QKV: C = A(4096x1024) @ [Wq;Wk;Wv](3072x1024)^T; BK=64 ----
// (R4 structure, verified best: 128x128 tile, 4 waves 2x2, XOR-swizzled LDS,
// glds width 16, direct epilogue)
__global__ __launch_bounds__(256) void gemm_qkv(
    const unsigned short* __restrict__ A, const unsigned short* __restrict__ W3,
    unsigned short* __restrict__ qb, unsigned short* __restrict__ kb,
    unsigned short* __restrict__ vt, float qscale) {
  __shared__ unsigned short As[128 * 64];  // 16 KB
  __shared__ unsigned short Bs[128 * 64];
  const int tid = threadIdx.x, lane = tid & 63, wid = tid >> 6;
  const int wm = wid >> 1, wn = wid & 1;
  const int quad = lane >> 4, c = lane & 15, cx = c & 7;
  const int nG = blockIdx.x * 128;
  const int wi = nG >> 10, nn0 = nG & 1023;
  const int m0 = blockIdx.y * 128;
  const unsigned short* Bsrc = W3 + (size_t)wi * 1048576;
  const int srow = lane >> 3;
  const int schk = ((lane & 7) ^ srow) * 8;
  const unsigned short* ag = A + (size_t)(m0 + wid * 32 + srow) * 1024 + schk;
  const unsigned short* bg = Bsrc + (size_t)(nn0 + wid * 32 + srow) * 1024 + schk;
  f32x4 acc[4][4] = {};
  for (int kk = 0; kk < 1024; kk += 64) {
#pragma unroll
    for (int i = 0; i < 4; ++i) {
      gl2lds(ag + (size_t)(i * 8) * 1024 + kk, &As[(wid * 32 + i * 8) * 64]);
      gl2lds(bg + (size_t)(i * 8) * 1024 + kk, &Bs[(wid * 32 + i * 8) * 64]);
    }
    __syncthreads();
#pragma unroll
    for (int kc = 0; kc < 2; ++kc) {
      bf16x8 a[4], b[4];
#pragma unroll
      for (int mt = 0; mt < 4; ++mt)
        a[mt] = *(const bf16x8*)(
            &As[(wm * 64 + mt * 16 + c) * 64 + ((kc * 4 + quad) ^ cx) * 8]);
#pragma unroll
      for (int nt = 0; nt < 4; ++nt)
        b[nt] = *(const bf16x8*)(
            &Bs[(wn * 64 + nt * 16 + c) * 64 + ((kc * 4 + quad) ^ cx) * 8]);
#pragma unroll
      for (int mt = 0; mt < 4; ++mt)
#pragma unroll
        for (int nt = 0; nt < 4; ++nt)
          acc[mt][nt] = mfma16(a[mt], b[nt], acc[mt][nt]);
    }
    __syncthreads();
  }
#pragma unroll
  for (int mt = 0; mt < 4; ++mt) {
#pragma unroll
    for (int nt = 0; nt < 4; ++nt) {
      const int mb = m0 + wm * 64 + mt * 16 + quad * 4;
      const int n = nn0 + wn * 64 + nt * 16 + c;
      const int hh = n >> 6, d = n & 63;
      const int bb = mb >> 11, ss = mb & 2047;
      if (wi == 0) {
#pragma unroll
        for (int r = 0; r < 4; ++r)
          qb[(size_t)((bb * NH + hh) * S_LEN + ss + r) * DH + d] =
              f2bf(acc[mt][nt][r] * qscale);
      } else if (wi == 1) {
#pragma unroll
        for (int r = 0; r < 4; ++r)
          kb[(size_t)((bb * NH + hh) * S_LEN + ss + r) * DH + d] =
              f2bf(acc[mt][nt][r]);
      } else {  // V^T: 4 regs = 4 consecutive s
        *(bf16x4*)(vt + (size_t)((bb * NH + hh) * DH + d) * S_LEN + ss) =
            cvt4(acc[mt][nt]);
      }
    }
  }
}

// ---- O projection: out = ctx(4096x1024) @ Wo^T + bo ----
// R20: 64x64 tiles, grid (16,64) = 1024 blocks = 4/CU (was 512 = 2/CU).
// Hypothesis: GEMMs are drain-latency-bound (MfmaUtil ~15%, 8x useful work
// per period); more, smaller resident blocks decorrelate the per-period
// vmcnt(0) drains (block X drains while Y/Z compute). LDS 16 KB, only
// 4 gl2lds/wave queued per period, low VGPR (acc[2][2]) -> more waves.
// Same R4 swizzle/fragment patterns at halved row counts.
__global__ __launch_bounds__(256) void gemm_out(
    const unsigned short* __restrict__ A, const unsigned short* __restrict__ W,
    float* __restrict__ out, const float* __restrict__ bias) {
  __shared__ unsigned short As[64 * 64];  // 8 KB
  __shared__ unsigned short Bs[64 * 64];  // 8 KB
  const int tid = threadIdx.x, lane = tid & 63, wid = tid >> 6;
  const int wm = wid >> 1, wn = wid & 1;
  const int quad = lane >> 4, c = lane & 15, cx = c & 7;
  const int n0 = blockIdx.x * 64, m0 = blockIdx.y * 64;
  const int srow = lane >> 3;
  const int schk = ((lane & 7) ^ srow) * 8;
  const unsigned short* ag = A + (size_t)(m0 + wid * 16 + srow) * 1024 + schk;
  const unsigned short* bg = W + (size_t)(n0 + wid * 16 + srow) * 1024 + schk;
  f32x4 acc[2][2] = {};
  for (int kk = 0; kk < 1024; kk += 64) {
#pragma unroll
    for (int i = 0; i < 2; ++i) {
      gl2lds(ag + (size_t)(i * 8) * 1024 + kk, &As[(wid * 16 + i * 8) * 64]);
      gl2lds(bg + (size_t)(i * 8) * 1024 + kk, &Bs[(wid * 16 + i * 8) * 64]);
    }
    __syncthreads();
#pragma unroll
    for (int kc = 0; kc < 2; ++kc) {
      bf16x8 a[2], b[2];
#pragma unroll
      for (int mt = 0; mt < 2; ++mt)
        a[mt] = *(const bf16x8*)(
            &As[(wm * 32 + mt * 16 + c) * 64 + ((kc * 4 + quad) ^ cx) * 8]);
#pragma unroll
      for (int nt = 0; nt < 2; ++nt)
        b[nt] = *(const bf16x8*)(
            &Bs[(wn * 32 + nt * 16 + c) * 64 + ((kc * 4 + quad) ^ cx) * 8]);
#pragma unroll
      for (int mt = 0; mt < 2; ++mt)
#pragma unroll
        for (int nt = 0; nt < 2; ++nt)
          acc[mt][nt] = mfma16(a[mt], b[nt], acc[mt][nt]);
    }
    __syncthreads();
  }
#pragma unroll
  for (int mt = 0; mt < 2; ++mt) {
#pragma unroll
    for (int nt = 0; nt < 2; ++nt) {
      const int mb = m0 + wm * 32 + mt * 16 + quad * 4;
      const int n = n0 + wn * 32 + nt * 16 + c;
      const float bv = bias[n];
#pragma unroll
      for (int r = 0; r < 4; ++r)
        out[(size_t)(mb + r) * D_MODEL + n] = acc[mt][nt][r] + bv;
    }
  }
}

// ---- flash attention, static-max softmax, 64 q per wave ----
// R11 attn (verified best): KVBLK=128 single-buffer, sigma-permuted K
// staging, in-register P, MFMA-pipe denominator, setprio around MFMA
// clusters.
__global__ __launch_bounds__(256, 2) void attn_kernel(
    const unsigned short* __restrict__ qb, const unsigned short* __restrict__ kb,
    const unsigned short* __restrict__ vt,
    const unsigned long long* __restrict__ mbits,
    unsigned short* __restrict__ ctx) {
  const int h = blockIdx.x, qt = blockIdx.y, b = blockIdx.z;
  const int bh = b * NH + h;
  const int tid = threadIdx.x, lane = tid & 63, wid = tid >> 6;
  const int quad = lane >> 4, c = lane & 15, cx = c & 7;
  const int qw = wid & 1, kh = wid >> 1;
  const int q0 = qt * 128;
  // KV staging: 2 sub-tiles x 32 KB = 64 KB; merge scratch overlays it.
  __shared__ __align__(16) char smem[65536];
  unsigned short* KVb = (unsigned short*)smem;

  const int qbase = q0 + qw * 64;
  const unsigned short* qp = qb + (size_t)(bh * S_LEN + qbase + c) * DH;
  bf16x8 bq[4][2];
#pragma unroll
  for (int sub = 0; sub < 4; ++sub) {
    bq[sub][0] = *(const bf16x8*)(qp + sub * 16 * DH + quad * 8);
    bq[sub][1] = *(const bf16x8*)(qp + sub * 16 * DH + 32 + quad * 8);
  }

  const bf16x8 onesv = {(__bf16)1.f, (__bf16)1.f, (__bf16)1.f, (__bf16)1.f,
                        (__bf16)1.f, (__bf16)1.f, (__bf16)1.f, (__bf16)1.f};

  f32x4 o[4][4] = {};
  float lacc[4] = {0.f, 0.f, 0.f, 0.f};
  const unsigned long long* mq0 =
      mbits + (size_t)(b * S_LEN + qbase + c) * 32 + kh * 16;

  const int srow = lane >> 3, schk = ((lane & 7) ^ srow) * 8;

  const unsigned short* gKb =
      kb + (size_t)(bh * S_LEN + (wid & 1) * 1024) * DH + schk;
  const unsigned short* gV =
      vt + (size_t)(bh * DH + srow) * S_LEN + (wid - 2) * 1024 + schk;

  for (int kt = 0; kt < 1024; kt += 128) {
    // stage both 64-key sub-tiles of this 128-key period
    if (wid < 2) {
#pragma unroll
      for (int hf = 0; hf < 2; ++hf)
#pragma unroll
        for (int i = 0; i < 8; ++i) {
          const int t = i * 8 + srow;
          const int st = (t & 0x23) | ((t >> 2) & 0x04) | ((t << 1) & 0x18);
          gl2lds(gKb + (size_t)(kt + hf * 64 + st) * DH,
                 &KVb[hf * 16384 + wid * 4096 + i * 512]);
        }
    } else {
#pragma unroll
      for (int hf = 0; hf < 2; ++hf)
#pragma unroll
        for (int i = 0; i < 8; ++i)
          gl2lds(gV + (size_t)(i * 8) * S_LEN + kt + hf * 64,
                 &KVb[hf * 16384 + wid * 4096 + i * 512]);
    }
    __syncthreads();  // (1) staging complete

#pragma unroll
    for (int hf = 0; hf < 2; ++hf) {
      const unsigned short* Ksh = KVb + hf * 16384 + kh * 4096;
      const unsigned short* Vsh = KVb + hf * 16384 + (2 + kh) * 4096;
      const int mi = (kt >> 6) + hf;

      // K-tile fragments, kept in regs across all 4 q-subgroups
      bf16x8 kf[8];
#pragma unroll
      for (int g = 0; g < 4; ++g) {
        const int rho = g * 16 + c;
        kf[2 * g] = *(const bf16x8*)(&Ksh[rho * 64 + (quad ^ cx) * 8]);
        kf[2 * g + 1] =
            *(const bf16x8*)(&Ksh[rho * 64 + ((4 + quad) ^ cx) * 8]);
      }

      bf16x8 bps[4][2];  // PV B-fragments, built in registers
#pragma unroll
      for (int sub = 0; sub < 4; ++sub) {
        f32x4 s[4];
        __builtin_amdgcn_s_setprio(1);
#pragma unroll
        for (int g = 0; g < 4; ++g) {
          f32x4 z = {};
          z = mfma16(kf[2 * g], bq[sub][0], z);
          z = mfma16(kf[2 * g + 1], bq[sub][1], z);
          s[g] = z;
        }
        __builtin_amdgcn_s_setprio(0);
        const unsigned long long w64 = mq0[sub * 512 + mi];
        const unsigned int wlo = (unsigned int)w64;
        const unsigned int whi = (unsigned int)(w64 >> 32);
        f32x4 p[4];
#pragma unroll
        for (int g = 0; g < 4; ++g) {
          // permuted key for (g,quad,r): (g>>1)*32 + quad*8 + (g&1)*4 + r
          const unsigned int bits =
              ((g & 2) ? whi : wlo) >> (quad * 8 + (g & 1) * 4);
#pragma unroll
          for (int r = 0; r < 4; ++r) {
            const float e = exp2raw(s[g][r]);
            p[g][r] = ((bits >> r) & 1u) ? 0.f : e;
          }
        }
        union { bf16x8 v; bf16x4 h[2]; } u0, u1;
        u0.h[0] = cvt4(p[0]); u0.h[1] = cvt4(p[1]);
        u1.h[0] = cvt4(p[2]); u1.h[1] = cvt4(p[3]);
        bps[sub][0] = u0.v;
        bps[sub][1] = u1.v;
        // denominator on the MFMA pipe: rows of ones x P^T = column sums;
        // every lane's z[0] = sum over this sub-tile's 64 keys for its q.
        f32x4 zs = {};
        zs = mfma16(onesv, bps[sub][0], zs);
        zs = mfma16(onesv, bps[sub][1], zs);
        lacc[sub] += zs[0];
      }

      // ctx^T += V^T . P^T  (V-frag read once, P straight from registers)
      __builtin_amdgcn_s_setprio(1);
#pragma unroll
      for (int ks = 0; ks < 2; ++ks) {
#pragma unroll
        for (int nt = 0; nt < 4; ++nt) {
          bf16x8 av = *(const bf16x8*)(
              &Vsh[(nt * 16 + c) * 64 + ((ks * 4 + quad) ^ cx) * 8]);
#pragma unroll
          for (int sub = 0; sub < 4; ++sub)
            o[sub][nt] = mfma16(av, bps[sub][ks], o[sub][nt]);
        }
      }
      __builtin_amdgcn_s_setprio(0);
    }
    __syncthreads();  // (2) both sub-tiles consumed; safe to restage
  }

  // merge key-halves via smem (KV dead after final barrier):
  // 8 panels of 16q x 68 floats + l array
  float* mrg = (float*)smem;
  float* ml = mrg + 8 * 1088;
  if (kh == 1) {
#pragma unroll
    for (int sub = 0; sub < 4; ++sub) {
      float* mo = mrg + (qw * 4 + sub) * 1088;
#pragma unroll
      for (int nt = 0; nt < 4; ++nt)
        *(f32x4*)(mo + c * 68 + nt * 16 + quad * 4) = o[sub][nt];
      if (quad == 0) ml[(qw * 4 + sub) * 16 + c] = lacc[sub];
    }
  }
  __syncthreads();
  if (kh == 0) {
#pragma unroll
    for (int sub = 0; sub < 4; ++sub) {
      const int pp = qw * 4 + sub;
      const float inv = 1.0f / (lacc[sub] + ml[pp * 16 + c]);
      const int q = qbase + sub * 16 + c;
      const float* mo = mrg + pp * 1088;
#pragma unroll
      for (int nt = 0; nt < 4; ++nt) {
        f32x4 ob = *(const f32x4*)(mo + c * 68 + nt * 16 + quad * 4);
        f32x4 rr = (o[sub][nt] + ob) * inv;
        *(bf16x4*)(ctx + (size_t)(b * S_LEN + q) * D_MODEL + h * DH + nt * 16 +
                   quad * 4) = cvt4(rr);
      }
    }
  }
}

extern "C" void kernel_launch(void* const* d_in, const int* in_sizes, int n_in,
                              void* d_out, int out_size, void* d_ws, size_t ws_size,
                              hipStream_t stream) {
  const float* query = (const float*)d_in[0];
  const int* mask = (const int*)d_in[1];
  const float* Wq = (const float*)d_in[2];
  const float* Wk = (const float*)d_in[3];
  const float* Wv = (const float*)d_in[4];
  const float* Wo = (const float*)d_in[5];
  const float* bo = (const float*)d_in[6];
  float* out = (float*)d_out;

  char* ws = (char*)d_ws;
  const size_t MB = 1024 * 1024;
  unsigned short* qbf = (unsigned short*)(ws);           // 8 MB; reused as ctx
  unsigned short* wbf = (unsigned short*)(ws + 8 * MB);  // 8 MB (Wq,Wk,Wv,Wo bf16)
  unsigned short* qb = (unsigned short*)(ws + 16 * MB);  // 8 MB
  unsigned short* kb = (unsigned short*)(ws + 24 * MB);  // 8 MB
  unsigned short* vt = (unsigned short*)(ws + 32 * MB);  // 8 MB
  unsigned long long* mb = (unsigned long long*)(ws + 40 * MB);  // 1 MB
  unsigned short* ctx = qbf;

  prep_kernel<<<8192 + 4096, 256, 0, stream>>>(query, Wq, Wk, Wv, Wo, mask,
                                               qbf, wbf, mb);

  // Q scaled by 1/sqrt(dh) * log2(e): softmax in exp2 domain
  gemm_qkv<<<dim3(3072 / 128, 4096 / 128), 256, 0, stream>>>(
      qbf, wbf, qb, kb, vt, 0.18033688f);

  attn_kernel<<<dim3(NH, S_LEN / 128, 2), 256, 0, stream>>>(qb, kb, vt, mb,
                                                            ctx);

  // 64x64 tiles, 1024 blocks = 4/CU (drain decorrelation)
  gemm_out<<<dim3(1024 / 64, 4096 / 64), 256, 0, stream>>>(
      ctx, wbf + 3 * 1048576, out, bo);
}

// Round 17
// 209.130 us; speedup vs baseline: 1.1419x; 1.0132x over previous
//
#include <hip/hip_runtime.h>

#define S_LEN 2048
#define D_MODEL 1024
#define NH 16
#define DH 64

typedef __bf16 bf16x8 __attribute__((ext_vector_type(8)));
typedef __bf16 bf16x4 __attribute__((ext_vector_type(4)));
typedef float f32x4 __attribute__((ext_vector_type(4)));
typedef unsigned long long ull2 __attribute__((ext_vector_type(2)));

__device__ __forceinline__ unsigned short f2bf(float f) {
  unsigned int x = __float_as_uint(f);
  x += 0x7fffu + ((x >> 16) & 1u);  // RNE
  return (unsigned short)(x >> 16);
}

__device__ __forceinline__ bf16x4 cvt4(f32x4 v) {
  return __builtin_convertvector(v, bf16x4);
}

__device__ __forceinline__ float exp2raw(float x) {
#if __has_builtin(__builtin_amdgcn_exp2f)
  return __builtin_amdgcn_exp2f(x);
#else
  return exp2f(x);
#endif
}

__device__ __forceinline__ f32x4 mfma16(bf16x8 a, bf16x8 b, f32x4 c) {
  return __builtin_amdgcn_mfma_f32_16x16x32_bf16(a, b, c, 0, 0, 0);
}

__device__ __forceinline__ void gl2lds(const unsigned short* g, unsigned short* l) {
  __builtin_amdgcn_global_load_lds(
      (__attribute__((address_space(1))) void*)g,
      (__attribute__((address_space(3))) void*)l, 16, 0, 0);
}

// ---- fused prep: pack mask bits (dense blocks 0..8191) + fp32->bf16 ----
// R19: 8192 blocks, each wave packs 4 u64-words via 4 coalesced dword loads
// + 4 ballots + two 16-B ull2 stores.
__global__ __launch_bounds__(256) void prep_kernel(
    const float* __restrict__ q, const float* __restrict__ wq,
    const float* __restrict__ wk, const float* __restrict__ wv,
    const float* __restrict__ wo, const int* __restrict__ mask,
    unsigned short* __restrict__ qbf, unsigned short* __restrict__ wbf,
    unsigned long long* __restrict__ bits) {
  const int bx = blockIdx.x;
  if (bx < 8192) {  // pack mask: 16 u64-words per block, 4 per wave
    const int wv = threadIdx.x >> 6, ln = threadIdx.x & 63;
    const long wbase = (long)bx * 16 + wv * 4;  // u64-word index
    unsigned long long w[4];
#pragma unroll
    for (int j = 0; j < 4; ++j)
      w[j] = __ballot(mask[(wbase + j) * 64 + ln] != 0);
    if (ln == 0) {
      ull2 lo = {w[0], w[1]}, hi = {w[2], w[3]};
      *(ull2*)(bits + wbase) = lo;
      *(ull2*)(bits + wbase + 2) = hi;
    }
  } else {  // convert 8 floats per thread
    const long t = (long)(bx - 8192) * 256 + threadIdx.x;
    const float* src;
    unsigned short* dst;
    long e;
    if (t < 524288) { src = q; dst = qbf; e = t * 8; }
    else {
      long u = t - 524288;
      int wi = (int)(u >> 17);
      e = (u & 131071) * 8;
      src = wi == 0 ? wq : wi == 1 ? wk : wi == 2 ? wv : wo;
      dst = wbf + (long)wi * 1048576;
    }
    float4 a = *(const float4*)(src + e);
    float4 b = *(const float4*)(src + e + 4);
    ushort4 p0 = {f2bf(a.x), f2bf(a.y), f2bf(a.z), f2bf(a.w)};
    ushort4 p1 = {f2bf(b.x), f2bf(b.y), f2bf(b.z), f2bf(b.w)};
    *(ushort4*)(dst + e) = p0;
    *(ushort4*)(dst + e + 4) = p1;
  }
}

// ---- fused QKV: C = A(4096x1024) @ [Wq;Wk;Wv](3072x1024)^T ----
// R21: 64x64 tiles (was 128x128). gemm_qkv was GRID-limited at 3 blocks/CU
// (768 blocks; MfmaUtil 14%, occ 13% -> drain-latency-bound). 3072 blocks,
// LDS 16 KB, acc[2][2] -> up to 8 blocks/CU: per-period vmcnt drains
// decorrelate across many more independent blocks (R20 mechanism, bigger
// target). n-range per block stays within one head (nn0 multiple of 64).
__global__ __launch_bounds__(256) void gemm_qkv(
    const unsigned short* __restrict__ A, const unsigned short* __restrict__ W3,
    unsigned short* __restrict__ qb, unsigned short* __restrict__ kb,
    unsigned short* __restrict__ vt, float qscale) {
  __shared__ unsigned short As[64 * 64];  // 8 KB
  __shared__ unsigned short Bs[64 * 64];  // 8 KB
  const int tid = threadIdx.x, lane = tid & 63, wid = tid >> 6;
  const int wm = wid >> 1, wn = wid & 1;
  const int quad = lane >> 4, c = lane & 15, cx = c & 7;
  const int n0 = blockIdx.x * 64;
  const int wi = n0 >> 10, nn0 = n0 & 1023;
  const int m0 = blockIdx.y * 64;
  const unsigned short* Bsrc = W3 + (size_t)wi * 1048576;
  const int srow = lane >> 3;
  const int schk = ((lane & 7) ^ srow) * 8;
  const unsigned short* ag = A + (size_t)(m0 + wid * 16 + srow) * 1024 + schk;
  const unsigned short* bg = Bsrc + (size_t)(nn0 + wid * 16 + srow) * 1024 + schk;
  f32x4 acc[2][2] = {};
  for (int kk = 0; kk < 1024; kk += 64) {
#pragma unroll
    for (int i = 0; i < 2; ++i) {
      gl2lds(ag + (size_t)(i * 8) * 1024 + kk, &As[(wid * 16 + i * 8) * 64]);
      gl2lds(bg + (size_t)(i * 8) * 1024 + kk, &Bs[(wid * 16 + i * 8) * 64]);
    }
    __syncthreads();
#pragma unroll
    for (int kc = 0; kc < 2; ++kc) {
      bf16x8 a[2], b[2];
#pragma unroll
      for (int mt = 0; mt < 2; ++mt)
        a[mt] = *(const bf16x8*)(
            &As[(wm * 32 + mt * 16 + c) * 64 + ((kc * 4 + quad) ^ cx) * 8]);
#pragma unroll
      for (int nt = 0; nt < 2; ++nt)
        b[nt] = *(const bf16x8*)(
            &Bs[(wn * 32 + nt * 16 + c) * 64 + ((kc * 4 + quad) ^ cx) * 8]);
#pragma unroll
      for (int mt = 0; mt < 2; ++mt)
#pragma unroll
        for (int nt = 0; nt < 2; ++nt)
          acc[mt][nt] = mfma16(a[mt], b[nt], acc[mt][nt]);
    }
    __syncthreads();
  }
#pragma unroll
  for (int mt = 0; mt < 2; ++mt) {
#pragma unroll
    for (int nt = 0; nt < 2; ++nt) {
      const int mb = m0 + wm * 32 + mt * 16 + quad * 4;
      const int n = nn0 + wn * 32 + nt * 16 + c;
      const int hh = n >> 6, d = n & 63;
      const int bb = mb >> 11, ss = mb & 2047;
      if (wi == 0) {
#pragma unroll
        for (int r = 0; r < 4; ++r)
          qb[(size_t)((bb * NH + hh) * S_LEN + ss + r) * DH + d] =
              f2bf(acc[mt][nt][r] * qscale);
      } else if (wi == 1) {
#pragma unroll
        for (int r = 0; r < 4; ++r)
          kb[(size_t)((bb * NH + hh) * S_LEN + ss + r) * DH + d] =
              f2bf(acc[mt][nt][r]);
      } else {  // V^T: 4 regs = 4 consecutive s
        *(bf16x4*)(vt + (size_t)((bb * NH + hh) * DH + d) * S_LEN + ss) =
            cvt4(acc[mt][nt]);
      }
    }
  }
}

// ---- O projection: out = ctx(4096x1024) @ Wo^T + bo; 64x64 (R20) ----
__global__ __launch_bounds__(256) void gemm_out(
    const unsigned short* __restrict__ A, const unsigned short* __restrict__ W,
    float* __restrict__ out, const float* __restrict__ bias) {
  __shared__ unsigned short As[64 * 64];  // 8 KB
  __shared__ unsigned short Bs[64 * 64];  // 8 KB
  const int tid = threadIdx.x, lane = tid & 63, wid = tid >> 6;
  const int wm = wid >> 1, wn = wid & 1;
  const int quad = lane >> 4, c = lane & 15, cx = c & 7;
  const int n0 = blockIdx.x * 64, m0 = blockIdx.y * 64;
  const int srow = lane >> 3;
  const int schk = ((lane & 7) ^ srow) * 8;
  const unsigned short* ag = A + (size_t)(m0 + wid * 16 + srow) * 1024 + schk;
  const unsigned short* bg = W + (size_t)(n0 + wid * 16 + srow) * 1024 + schk;
  f32x4 acc[2][2] = {};
  for (int kk = 0; kk < 1024; kk += 64) {
#pragma unroll
    for (int i = 0; i < 2; ++i) {
      gl2lds(ag + (size_t)(i * 8) * 1024 + kk, &As[(wid * 16 + i * 8) * 64]);
      gl2lds(bg + (size_t)(i * 8) * 1024 + kk, &Bs[(wid * 16 + i * 8) * 64]);
    }
    __syncthreads();
#pragma unroll
    for (int kc = 0; kc < 2; ++kc) {
      bf16x8 a[2], b[2];
#pragma unroll
      for (int mt = 0; mt < 2; ++mt)
        a[mt] = *(const bf16x8*)(
            &As[(wm * 32 + mt * 16 + c) * 64 + ((kc * 4 + quad) ^ cx) * 8]);
#pragma unroll
      for (int nt = 0; nt < 2; ++nt)
        b[nt] = *(const bf16x8*)(
            &Bs[(wn * 32 + nt * 16 + c) * 64 + ((kc * 4 + quad) ^ cx) * 8]);
#pragma unroll
      for (int mt = 0; mt < 2; ++mt)
#pragma unroll
        for (int nt = 0; nt < 2; ++nt)
          acc[mt][nt] = mfma16(a[mt], b[nt], acc[mt][nt]);
    }
    __syncthreads();
  }
#pragma unroll
  for (int mt = 0; mt < 2; ++mt) {
#pragma unroll
    for (int nt = 0; nt < 2; ++nt) {
      const int mb = m0 + wm * 32 + mt * 16 + quad * 4;
      const int n = n0 + wn * 32 + nt * 16 + c;
      const float bv = bias[n];
#pragma unroll
      for (int r = 0; r < 4; ++r)
        out[(size_t)(mb + r) * D_MODEL + n] = acc[mt][nt][r] + bv;
    }
  }
}

// ---- flash attention, static-max softmax, 64 q per wave ----
// R11 attn (verified best): KVBLK=128 single-buffer, sigma-permuted K
// staging, in-register P, MFMA-pipe denominator, setprio around MFMA
// clusters.
__global__ __launch_bounds__(256, 2) void attn_kernel(
    const unsigned short* __restrict__ qb, const unsigned short* __restrict__ kb,
    const unsigned short* __restrict__ vt,
    const unsigned long long* __restrict__ mbits,
    unsigned short* __restrict__ ctx) {
  const int h = blockIdx.x, qt = blockIdx.y, b = blockIdx.z;
  const int bh = b * NH + h;
  const int tid = threadIdx.x, lane = tid & 63, wid = tid >> 6;
  const int quad = lane >> 4, c = lane & 15, cx = c & 7;
  const int qw = wid & 1, kh = wid >> 1;
  const int q0 = qt * 128;
  // KV staging: 2 sub-tiles x 32 KB = 64 KB; merge scratch overlays it.
  __shared__ __align__(16) char smem[65536];
  unsigned short* KVb = (unsigned short*)smem;

  const int qbase = q0 + qw * 64;
  const unsigned short* qp = qb + (size_t)(bh * S_LEN + qbase + c) * DH;
  bf16x8 bq[4][2];
#pragma unroll
  for (int sub = 0; sub < 4; ++sub) {
    bq[sub][0] = *(const bf16x8*)(qp + sub * 16 * DH + quad * 8);
    bq[sub][1] = *(const bf16x8*)(qp + sub * 16 * DH + 32 + quad * 8);
  }

  const bf16x8 onesv = {(__bf16)1.f, (__bf16)1.f, (__bf16)1.f, (__bf16)1.f,
                        (__bf16)1.f, (__bf16)1.f, (__bf16)1.f, (__bf16)1.f};

  f32x4 o[4][4] = {};
  float lacc[4] = {0.f, 0.f, 0.f, 0.f};
  const unsigned long long* mq0 =
      mbits + (size_t)(b * S_LEN + qbase + c) * 32 + kh * 16;

  const int srow = lane >> 3, schk = ((lane & 7) ^ srow) * 8;

  const unsigned short* gKb =
      kb + (size_t)(bh * S_LEN + (wid & 1) * 1024) * DH + schk;
  const unsigned short* gV =
      vt + (size_t)(bh * DH + srow) * S_LEN + (wid - 2) * 1024 + schk;

  for (int kt = 0; kt < 1024; kt += 128) {
    // stage both 64-key sub-tiles of this 128-key period
    if (wid < 2) {
#pragma unroll
      for (int hf = 0; hf < 2; ++hf)
#pragma unroll
        for (int i = 0; i < 8; ++i) {
          const int t = i * 8 + srow;
          const int st = (t & 0x23) | ((t >> 2) & 0x04) | ((t << 1) & 0x18);
          gl2lds(gKb + (size_t)(kt + hf * 64 + st) * DH,
                 &KVb[hf * 16384 + wid * 4096 + i * 512]);
        }
    } else {
#pragma unroll
      for (int hf = 0; hf < 2; ++hf)
#pragma unroll
        for (int i = 0; i < 8; ++i)
          gl2lds(gV + (size_t)(i * 8) * S_LEN + kt + hf * 64,
                 &KVb[hf * 16384 + wid * 4096 + i * 512]);
    }
    __syncthreads();  // (1) staging complete

#pragma unroll
    for (int hf = 0; hf < 2; ++hf) {
      const unsigned short* Ksh = KVb + hf * 16384 + kh * 4096;
      const unsigned short* Vsh = KVb + hf * 16384 + (2 + kh) * 4096;
      const int mi = (kt >> 6) + hf;

      // K-tile fragments, kept in regs across all 4 q-subgroups
      bf16x8 kf[8];
#pragma unroll
      for (int g = 0; g < 4; ++g) {
        const int rho = g * 16 + c;
        kf[2 * g] = *(const bf16x8*)(&Ksh[rho * 64 + (quad ^ cx) * 8]);
        kf[2 * g + 1] =
            *(const bf16x8*)(&Ksh[rho * 64 + ((4 + quad) ^ cx) * 8]);
      }

      bf16x8 bps[4][2];  // PV B-fragments, built in registers
#pragma unroll
      for (int sub = 0; sub < 4; ++sub) {
        f32x4 s[4];
        __builtin_amdgcn_s_setprio(1);
#pragma unroll
        for (int g = 0; g < 4; ++g) {
          f32x4 z = {};
          z = mfma16(kf[2 * g], bq[sub][0], z);
          z = mfma16(kf[2 * g + 1], bq[sub][1], z);
          s[g] = z;
        }
        __builtin_amdgcn_s_setprio(0);
        const unsigned long long w64 = mq0[sub * 512 + mi];
        const unsigned int wlo = (unsigned int)w64;
        const unsigned int whi = (unsigned int)(w64 >> 32);
        f32x4 p[4];
#pragma unroll
        for (int g = 0; g < 4; ++g) {
          // permuted key for (g,quad,r): (g>>1)*32 + quad*8 + (g&1)*4 + r
          const unsigned int bits =
              ((g & 2) ? whi : wlo) >> (quad * 8 + (g & 1) * 4);
#pragma unroll
          for (int r = 0; r < 4; ++r) {
            const float e = exp2raw(s[g][r]);
            p[g][r] = ((bits >> r) & 1u) ? 0.f : e;
          }
        }
        union { bf16x8 v; bf16x4 h[2]; } u0, u1;
        u0.h[0] = cvt4(p[0]); u0.h[1] = cvt4(p[1]);
        u1.h[0] = cvt4(p[2]); u1.h[1] = cvt4(p[3]);
        bps[sub][0] = u0.v;
        bps[sub][1] = u1.v;
        // denominator on the MFMA pipe: rows of ones x P^T = column sums;
        // every lane's z[0] = sum over this sub-tile's 64 keys for its q.
        f32x4 zs = {};
        zs = mfma16(onesv, bps[sub][0], zs);
        zs = mfma16(onesv, bps[sub][1], zs);
        lacc[sub] += zs[0];
      }

      // ctx^T += V^T . P^T  (V-frag read once, P straight from registers)
      __builtin_amdgcn_s_setprio(1);
#pragma unroll
      for (int ks = 0; ks < 2; ++ks) {
#pragma unroll
        for (int nt = 0; nt < 4; ++nt) {
          bf16x8 av = *(const bf16x8*)(
              &Vsh[(nt * 16 + c) * 64 + ((ks * 4 + quad) ^ cx) * 8]);
#pragma unroll
          for (int sub = 0; sub < 4; ++sub)
            o[sub][nt] = mfma16(av, bps[sub][ks], o[sub][nt]);
        }
      }
      __builtin_amdgcn_s_setprio(0);
    }
    __syncthreads();  // (2) both sub-tiles consumed; safe to restage
  }

  // merge key-halves via smem (KV dead after final barrier):
  // 8 panels of 16q x 68 floats + l array
  float* mrg = (float*)smem;
  float* ml = mrg + 8 * 1088;
  if (kh == 1) {
#pragma unroll
    for (int sub = 0; sub < 4; ++sub) {
      float* mo = mrg + (qw * 4 + sub) * 1088;
#pragma unroll
      for (int nt = 0; nt < 4; ++nt)
        *(f32x4*)(mo + c * 68 + nt * 16 + quad * 4) = o[sub][nt];
      if (quad == 0) ml[(qw * 4 + sub) * 16 + c] = lacc[sub];
    }
  }
  __syncthreads();
  if (kh == 0) {
#pragma unroll
    for (int sub = 0; sub < 4; ++sub) {
      const int pp = qw * 4 + sub;
      const float inv = 1.0f / (lacc[sub] + ml[pp * 16 + c]);
      const int q = qbase + sub * 16 + c;
      const float* mo = mrg + pp * 1088;
#pragma unroll
      for (int nt = 0; nt < 4; ++nt) {
        f32x4 ob = *(const f32x4*)(mo + c * 68 + nt * 16 + quad * 4);
        f32x4 rr = (o[sub][nt] + ob) * inv;
        *(bf16x4*)(ctx + (size_t)(b * S_LEN + q) * D_MODEL + h * DH + nt * 16 +
                   quad * 4) = cvt4(rr);
      }
    }
  }
}

extern "C" void kernel_launch(void* const* d_in, const int* in_sizes, int n_in,
                              void* d_out, int out_size, void* d_ws, size_t ws_size,
                              hipStream_t stream) {
  const float* query = (const float*)d_in[0];
  const int* mask = (const int*)d_in[1];
  const float* Wq = (const float*)d_in[2];
  const float* Wk = (const float*)d_in[3];
  const float* Wv = (const float*)d_in[4];
  const float* Wo = (const float*)d_in[5];
  const float* bo = (const float*)d_in[6];
  float* out = (float*)d_out;

  char* ws = (char*)d_ws;
  const size_t MB = 1024 * 1024;
  unsigned short* qbf = (unsigned short*)(ws);           // 8 MB; reused as ctx
  unsigned short* wbf = (unsigned short*)(ws + 8 * MB);  // 8 MB (Wq,Wk,Wv,Wo bf16)
  unsigned short* qb = (unsigned short*)(ws + 16 * MB);  // 8 MB
  unsigned short* kb = (unsigned short*)(ws + 24 * MB);  // 8 MB
  unsigned short* vt = (unsigned short*)(ws + 32 * MB);  // 8 MB
  unsigned long long* mb = (unsigned long long*)(ws + 40 * MB);  // 1 MB
  unsigned short* ctx = qbf;

  prep_kernel<<<8192 + 4096, 256, 0, stream>>>(query, Wq, Wk, Wv, Wo, mask,
                                               qbf, wbf, mb);

  // Q scaled by 1/sqrt(dh) * log2(e): softmax in exp2 domain.
  // 64x64 tiles: 3072 blocks (drain decorrelation, was 768)
  gemm_qkv<<<dim3(3072 / 64, 4096 / 64), 256, 0, stream>>>(
      qbf, wbf, qb, kb, vt, 0.18033688f);

  attn_kernel<<<dim3(NH, S_LEN / 128, 2), 256, 0, stream>>>(qb, kb, vt, mb,
                                                            ctx);

  // 64x64 tiles, 1024 blocks = 4/CU (drain decorrelation)
  gemm_out<<<dim3(1024 / 64, 4096 / 64), 256, 0, stream>>>(
      ctx, wbf + 3 * 1048576, out, bo);
}